// Round 11
// baseline (526.419 us; speedup 1.0000x reference)
//
#include <hip/hip_runtime.h>
#include <math.h>

// ---------------------------------------------------------------------------
// GAT network: 4 layers, N=50000 nodes, E=1.6M edges, edge_dim=8.
// CSR build (all global writes coalesced): bin -> count -> scan -> place.
// eid[slot] carries (e | dl<<21). edge_prep2: slot-dense per-128-node blocks;
// self-loop dots = row mean of edge dots (linearity). H=2 layers: two
// per-head passes over head-major planes; ping-pong gather loops.
// ---------------------------------------------------------------------------

#define GSZ 256      // nodes per coarse bucket (bucket = dst>>8)
#define CAPB 10240   // per-bucket region capacity (avg fill 8192, 22 sigma)
#define CHUNK 4096   // edges per bin block
#define CAP_C 9984   // place stage capacity (avg span 8448, 17 sigma)
#define NPB 128      // nodes per edge_prep2 block

__device__ __forceinline__ float wave_sum64(float v) {
#pragma unroll
  for (int o = 32; o >= 1; o >>= 1) v += __shfl_xor(v, o);
  return v;
}
__device__ __forceinline__ float dot8(const float4& a, const float4& b,
                                      const float* c) {
  return a.x * c[0] + a.y * c[1] + a.z * c[2] + a.w * c[3] + b.x * c[4] +
         b.y * c[5] + b.z * c[6] + b.w * c[7];
}

// --------------------------- CSR build ------------------------------------

__global__ __launch_bounds__(256) void bin_kernel(const int* __restrict__ src,
                                                  const int* __restrict__ dst,
                                                  int* __restrict__ bfill,
                                                  int2* __restrict__ bbuf,
                                                  int E_) {
  __shared__ int histo[256];
  __shared__ int scanb[256];
  __shared__ int segstart[256];
  __shared__ int gbase[256];
  __shared__ int cur[256];
  __shared__ int2 stage[CHUNK];
  __shared__ int gtarg[CHUNK];
  const int t = threadIdx.x;
  const int e0 = blockIdx.x * CHUNK;
  const int cnt = min(CHUNK, E_ - e0);
  histo[t] = 0;
  __syncthreads();
  int myd[CHUNK / 256];
#pragma unroll
  for (int k = 0; k < CHUNK / 256; ++k) {
    int i = t + k * 256;
    int d = -1;
    if (i < cnt) {
      d = dst[e0 + i];
      atomicAdd(&histo[d >> 8], 1);
    }
    myd[k] = d;
  }
  __syncthreads();
  const int v = histo[t];
  int acc = v;
  scanb[t] = v;
  __syncthreads();
#pragma unroll
  for (int o = 1; o < 256; o <<= 1) {
    int u = (t >= o) ? scanb[t - o] : 0;
    __syncthreads();
    acc += u;
    scanb[t] = acc;
    __syncthreads();
  }
  int gp = 0;
  if (v > 0) gp = atomicAdd(&bfill[t], v);  // t = bucket id
  segstart[t] = acc - v;                    // exclusive
  gbase[t] = t * CAPB + min(gp, CAPB - v);  // clamp (never triggers)
  cur[t] = 0;
  __syncthreads();
#pragma unroll
  for (int k = 0; k < CHUNK / 256; ++k) {
    int i = t + k * 256;
    int d = myd[k];
    if (d >= 0) {
      int b = d >> 8;
      int s = src[e0 + i];
      int p = atomicAdd(&cur[b], 1);
      int sl = segstart[b] + p;
      stage[sl] = make_int2(s, (e0 + i) | ((d & 255) << 21));
      gtarg[sl] = gbase[b] + p;
    }
  }
  __syncthreads();
  for (int i = t; i < cnt; i += 256) bbuf[gtarg[i]] = stage[i];
}

__global__ __launch_bounds__(256) void count_kernel(
    const int* __restrict__ bfill, const int2* __restrict__ bbuf,
    int* __restrict__ cnt, int n) {
  __shared__ int h[256];
  const int b = blockIdx.x;
  const int t = threadIdx.x;
  h[t] = 0;
  __syncthreads();
  const int m = min(bfill[b], CAPB);
  const int2* reg = bbuf + (size_t)b * CAPB;
  for (int i = t; i < m; i += 256) {
    int dl = ((unsigned)reg[i].y) >> 21;
    atomicAdd(&h[dl], 1);
  }
  __syncthreads();
  int node = b * GSZ + t;
  if (node < n) cnt[node] = h[t];
}

__global__ __launch_bounds__(256) void scan1_kernel(const int* __restrict__ cnt,
                                                    int* __restrict__ rowp,
                                                    int* __restrict__ bsum,
                                                    int n) {
  __shared__ int sd[256];
  const int t = threadIdx.x;
  const int base = blockIdx.x * 1024 + t * 4;
  int v0 = (base + 0 < n) ? cnt[base + 0] + 1 : 0;
  int v1 = (base + 1 < n) ? cnt[base + 1] + 1 : 0;
  int v2 = (base + 2 < n) ? cnt[base + 2] + 1 : 0;
  int v3 = (base + 3 < n) ? cnt[base + 3] + 1 : 0;
  const int s = v0 + v1 + v2 + v3;
  sd[t] = s;
  __syncthreads();
  int acc = s;
#pragma unroll
  for (int o = 1; o < 256; o <<= 1) {
    int u = (t >= o) ? sd[t - o] : 0;
    __syncthreads();
    acc += u;
    sd[t] = acc;
    __syncthreads();
  }
  int excl = acc - s;
  if (base + 0 < n) rowp[base + 0] = excl;
  if (base + 1 < n) rowp[base + 1] = excl + v0;
  if (base + 2 < n) rowp[base + 2] = excl + v0 + v1;
  if (base + 3 < n) rowp[base + 3] = excl + v0 + v1 + v2;
  if (t == 255) bsum[blockIdx.x] = acc;
}

__global__ void scan2_kernel(int* __restrict__ bsum, int nb) {
  const int lane = threadIdx.x;
  int v = (lane < nb) ? bsum[lane] : 0;
  int incl = v;
#pragma unroll
  for (int o = 1; o < 64; o <<= 1) {
    int u = __shfl_up(incl, o);
    if (lane >= o) incl += u;
  }
  if (lane < nb) bsum[lane] = incl - v;
  if (lane == 63) bsum[nb] = incl;
}

__global__ void scan3_kernel(int* __restrict__ rowp,
                             const int* __restrict__ bsum, int n, int nb) {
  int i = blockIdx.x * 256 + threadIdx.x;
  if (i >= n) return;
  rowp[i] += bsum[i >> 10];
  if (i == 0) rowp[n] = bsum[nb];
}

// place bucket edges into exact CSR slots; eid keeps (e | dl<<21) packed.
__global__ __launch_bounds__(256) void place_kernel(
    const int* __restrict__ rowp, const int* __restrict__ bfill,
    const int2* __restrict__ bbuf, int* __restrict__ col_src,
    int* __restrict__ eidA, int n, int E_) {
  __shared__ int rp[GSZ + 1];
  __shared__ int cur[GSZ];
  __shared__ int2 stage[CAP_C];
  const int b = blockIdx.x;
  const int t = threadIdx.x;
  const int lo = b * GSZ;
  const int nk = min(GSZ, n - lo);
  for (int i = t; i <= nk; i += 256) rp[i] = rowp[lo + i];  // covers rp[256]!
  cur[t] = 0;
  __syncthreads();
  const int s0 = rp[0];
  const int span = rp[nk] - s0;
  const bool fits = (span <= CAP_C);
  const int m = min(bfill[b], CAPB);
  const int2* reg = bbuf + (size_t)b * CAPB;
  for (int i = t; i < m; i += 256) {
    int2 pl = reg[i];
    int dl = ((unsigned)pl.y) >> 21;
    int p = atomicAdd(&cur[dl], 1);
    int slot = rp[dl] + p;
    if (fits) stage[slot - s0] = pl;  // keep dl packed in .y
    else { col_src[slot] = pl.x; eidA[slot] = pl.y; }
  }
  if (t < nk) {  // self entry: last slot of each row; pack dl = t
    int slot = rp[t + 1] - 1;
    int node = lo + t;
    int pv = (E_ + node) | (t << 21);
    if (fits) stage[slot - s0] = make_int2(node, pv);
    else { col_src[slot] = node; eidA[slot] = pv; }
  }
  __syncthreads();
  if (fits) {
    for (int i = t; i < span; i += 256) {
      int2 v = stage[i];
      col_src[s0 + i] = v.x;
      eidA[s0 + i] = v.y;
    }
  }
}

// --------------------------- comb (all layers) ------------------------------
__global__ void comb_all_kernel(const float* __restrict__ We0,
                                const float* __restrict__ ae0,
                                const float* __restrict__ We1,
                                const float* __restrict__ ae1,
                                const float* __restrict__ We2,
                                const float* __restrict__ ae2,
                                const float* __restrict__ We3,
                                const float* __restrict__ ae3,
                                float* __restrict__ comb) {
  int t = threadIdx.x;
  if (t >= 48) return;
  float s = 0.f;
  if (t < 8) {
    int d = t;
    for (int c = 0; c < 64; ++c) s += We0[d * 64 + c] * ae0[c];
  } else if (t < 24) {
    int idx = t - 8, h = idx >> 3, d = idx & 7;
    for (int c = 0; c < 64; ++c) s += We1[d * 128 + h * 64 + c] * ae1[h * 64 + c];
  } else if (t < 40) {
    int idx = t - 24, h = idx >> 3, d = idx & 7;
    for (int c = 0; c < 64; ++c) s += We2[d * 128 + h * 64 + c] * ae2[h * 64 + c];
  } else {
    int d = t - 40;
    for (int c = 0; c < 2; ++c) s += We3[d * 2 + c] * ae3[c];
  }
  comb[t] = s;
}

// --------------------------- edge prep (slot-dense) -------------------------
// Block = 128 consecutive nodes. Pass 1: iterate the block's CSR span densely,
// gather ea[e], write 6 edot planes (skip self slots). Pass 2: self-slot dot =
// mean of the row's edge dots (dot is linear in the attr), rows are L2-hot.
__global__ __launch_bounds__(256) void edge_prep2_kernel(
    const int* __restrict__ rowp, const int* __restrict__ eid,
    const float* __restrict__ ea, const float* __restrict__ comb,
    float* __restrict__ edot0, float* __restrict__ e1a,
    float* __restrict__ e1b, float* __restrict__ e2a,
    float* __restrict__ e2b, float* __restrict__ edot3, int n, int E_) {
  __shared__ float cb[48];
  __shared__ int rp[NPB + 1];
  const int t = threadIdx.x;
  if (t < 48) cb[t] = comb[t];
  const int lo = blockIdx.x * NPB;
  const int nk = min(NPB, n - lo);
  for (int i = t; i <= nk; i += 256) rp[i] = rowp[lo + i];
  __syncthreads();
  const int s0 = rp[0];
  const int span = rp[nk] - s0;

  for (int i = t; i < span; i += 256) {
    int v = eid[s0 + i];
    int e = v & 0x1FFFFF;
    if (e < E_) {
      const float4* p = reinterpret_cast<const float4*>(ea + (size_t)e * 8);
      float4 a = p[0], b = p[1];
      int slot = s0 + i;
      edot0[slot] = dot8(a, b, cb + 0);
      e1a[slot] = dot8(a, b, cb + 8);
      e1b[slot] = dot8(a, b, cb + 16);
      e2a[slot] = dot8(a, b, cb + 24);
      e2b[slot] = dot8(a, b, cb + 32);
      edot3[slot] = dot8(a, b, cb + 40);
    }
  }
  __syncthreads();

  if (t < nk) {
    const int a = rp[t];
    const int b = rp[t + 1];  // self at b-1
    const int deg = b - 1 - a;
    float s0s = 0.f, s1s = 0.f, s2s = 0.f, s3s = 0.f, s4s = 0.f, s5s = 0.f;
    for (int j = a; j < b - 1; ++j) {
      s0s += edot0[j];
      s1s += e1a[j];
      s2s += e1b[j];
      s3s += e2a[j];
      s4s += e2b[j];
      s5s += edot3[j];
    }
    const float inv = 1.f / fmaxf((float)deg, 1.f);
    edot0[b - 1] = s0s * inv;
    e1a[b - 1] = s1s * inv;
    e1b[b - 1] = s2s * inv;
    e2a[b - 1] = s3s * inv;
    e2b[b - 1] = s4s * inv;
    edot3[b - 1] = s5s * inv;
  }
}

// --------------------------- projection GEMM -------------------------------
// h = x @ W; H==2: head-major planes h + h*n*64. al_src/al_dst head-major
// [h][n] (H==1 indexing degenerates to [n]).
template <int HC, int H>
__global__ __launch_bounds__(256) void gemm_proj_kernel(
    const float* __restrict__ x, const float* __restrict__ W,
    const float* __restrict__ a_src, const float* __restrict__ a_dst,
    float* __restrict__ h, float* __restrict__ al_src,
    float* __restrict__ al_dst, int n) {
  constexpr int IN = 64;
  constexpr int C = HC / H;
  __shared__ float xs[32][IN];
  const int tid = threadIdx.x;
  const int j = tid % HC;
  const int rsub = tid / HC;
  constexpr int RPP = 256 / HC > 0 ? 256 / HC : 1;

  float wr[IN];
#pragma unroll
  for (int k = 0; k < IN; ++k) wr[k] = W[k * HC + j];
  const float asj = a_src[j];
  const float adj = a_dst[j];

  const int row0 = blockIdx.x * 32;
  {
    const float4* xv = reinterpret_cast<const float4*>(x);
    float4* xsv = reinterpret_cast<float4*>(&xs[0][0]);
    for (int i = tid; i < 32 * IN / 4; i += 256) {
      int r = i / (IN / 4);
      int row = row0 + r;
      float4 v = make_float4(0.f, 0.f, 0.f, 0.f);
      if (row < n) v = xv[(size_t)row * (IN / 4) + (i % (IN / 4))];
      xsv[i] = v;
    }
  }
  __syncthreads();

  for (int rb = 0; rb < 32; rb += RPP) {
    int r = rb + rsub;
    if (r >= 32) break;  // wave-uniform (only for HC=2 tails)
    int row = row0 + r;
    float acc = 0.f;
#pragma unroll
    for (int k4 = 0; k4 < IN / 4; ++k4) {
      float4 xv = *reinterpret_cast<const float4*>(&xs[r][k4 * 4]);
      acc += xv.x * wr[k4 * 4 + 0] + xv.y * wr[k4 * 4 + 1] +
             xv.z * wr[k4 * 4 + 2] + xv.w * wr[k4 * 4 + 3];
    }
    if (row < n) {
      size_t oidx = (H == 2)
                        ? ((size_t)(j >> 6) * ((size_t)n * 64) +
                           (size_t)row * 64 + (j & 63))
                        : ((size_t)row * HC + j);
      h[oidx] = acc;
    }
    float ps = acc * asj;
    float pd = acc * adj;
#pragma unroll
    for (int o = C / 2; o >= 1; o >>= 1) {
      ps += __shfl_xor(ps, o);
      pd += __shfl_xor(pd, o);
    }
    if (row < n && (j % C) == 0) {
      int hh = j / C;
      al_src[(size_t)hh * n + row] = ps;
      al_dst[(size_t)hh * n + row] = pd;
    }
  }
}

// ------------------- fused node kernel (H=1 layers) -------------------------
template <int C, bool RELU>
__global__ __launch_bounds__(256) void gat_node_kernel(
    const int* __restrict__ row_ptr, const int* __restrict__ col_src,
    const float* __restrict__ edot, const float* __restrict__ h_proj,
    const float* __restrict__ al_src, const float* __restrict__ al_dst,
    const float* __restrict__ bias, float* __restrict__ out, int n) {
  const int lane = threadIdx.x & 63;
  const int node = blockIdx.x * 4 + (threadIdx.x >> 6);
  if (node >= n) return;

  const float adn = al_dst[node];
  const int start = row_ptr[node];
  const int end = row_ptr[node + 1];

  float denp = 0.f;
  float4 acc4 = make_float4(0.f, 0.f, 0.f, 0.f);
  float accp = 0.f;  // C==2 path accumulator

  const int sub = lane & 15;    // channel quad
  const int grp16 = lane >> 4;  // edge slot within group-of-4

  for (int base = start; base < end; base += 64) {
    const int i = base + lane;
    const bool valid = (i < end);
    int s = 0;
    float ex = 0.f;
    if (valid) {
      s = col_src[i];
      float a = al_src[s] + adn + edot[i];
      a = (a > 0.f) ? a : 0.2f * a;
      ex = __expf(a);
    }
    denp += ex;

    const int cntc = min(64, end - base);
    if (C == 2) {
      const int half = lane >> 1;
      const int ch = lane & 1;
#pragma unroll
      for (int sb = 0; sb < 2; ++sb) {
        int tt = sb * 32 + half;
        int sv = __shfl(s, tt);
        float w = __shfl(ex, tt);
        if (tt < cntc) accp += w * h_proj[sv * 2 + ch];
      }
    } else {
      // register ping-pong: two 4-load batches in flight
      auto issue = [&](int g, float4 (&v)[4], float (&w)[4]) {
#pragma unroll
        for (int u = 0; u < 4; ++u) {
          int tt = (g * 4 + u) * 4 + grp16;  // <= 63; overshoot lanes ex=0
          int sv = __shfl(s, tt);
          w[u] = __shfl(ex, tt);
          v[u] = *reinterpret_cast<const float4*>(h_proj + (size_t)sv * 64 +
                                                  sub * 4);
        }
      };
      auto fma4 = [&](float4 (&v)[4], float (&w)[4]) {
#pragma unroll
        for (int u = 0; u < 4; ++u) {
          acc4.x += w[u] * v[u].x; acc4.y += w[u] * v[u].y;
          acc4.z += w[u] * v[u].z; acc4.w += w[u] * v[u].w;
        }
      };
      const int nbat = (cntc + 15) >> 4;  // batches of 16 edges, <= 4
      float4 va[4], vb[4];
      float wa[4], wb[4];
      issue(0, va, wa);
      int g = 0;
      for (;;) {
        if (g + 1 < nbat) issue(g + 1, vb, wb);
        fma4(va, wa);
        if (++g >= nbat) break;
        if (g + 1 < nbat) issue(g + 1, va, wa);
        fma4(vb, wb);
        if (++g >= nbat) break;
      }
    }
  }

  const float den = wave_sum64(denp);

  if (C == 2) {
#pragma unroll
    for (int o = 2; o <= 32; o <<= 1) accp += __shfl_xor(accp, o);
    if (lane < 2) {
      float v = accp / (den + 1e-16f) + bias[lane];
      if (RELU) v = fmaxf(v, 0.f);
      out[node * 2 + lane] = v;
    }
  } else {
    acc4.x += __shfl_xor(acc4.x, 16); acc4.x += __shfl_xor(acc4.x, 32);
    acc4.y += __shfl_xor(acc4.y, 16); acc4.y += __shfl_xor(acc4.y, 32);
    acc4.z += __shfl_xor(acc4.z, 16); acc4.z += __shfl_xor(acc4.z, 32);
    acc4.w += __shfl_xor(acc4.w, 16); acc4.w += __shfl_xor(acc4.w, 32);
    if (lane < 16) {
      float inv = 1.f / (den + 1e-16f);
      float4 bv = *reinterpret_cast<const float4*>(bias + sub * 4);
      float4 o;
      o.x = acc4.x * inv + bv.x; o.y = acc4.y * inv + bv.y;
      o.z = acc4.z * inv + bv.z; o.w = acc4.w * inv + bv.w;
      if (RELU) {
        o.x = fmaxf(o.x, 0.f); o.y = fmaxf(o.y, 0.f);
        o.z = fmaxf(o.z, 0.f); o.w = fmaxf(o.w, 0.f);
      }
      *reinterpret_cast<float4*>(out + (size_t)node * 64 + sub * 4) = o;
    }
  }
}

// ------------------- per-head pass kernel (H=2 layers) ----------------------
template <bool FIRST>
__global__ __launch_bounds__(256) void gat_head_kernel(
    const int* __restrict__ row_ptr, const int* __restrict__ col_src,
    const float* __restrict__ edotH, const float* __restrict__ hplane,
    const float* __restrict__ al_srcH, const float* __restrict__ al_dstH,
    const float* __restrict__ bias, float* __restrict__ partial,
    float* __restrict__ out, int n) {
  const int lane = threadIdx.x & 63;
  const int node = blockIdx.x * 4 + (threadIdx.x >> 6);
  if (node >= n) return;

  const float adn = al_dstH[node];
  const int start = row_ptr[node];
  const int end = row_ptr[node + 1];

  float denp = 0.f;
  float4 acc4 = make_float4(0.f, 0.f, 0.f, 0.f);

  const int sub = lane & 15;
  const int grp16 = lane >> 4;

  for (int base = start; base < end; base += 64) {
    const int i = base + lane;
    const bool valid = (i < end);
    int s = 0;
    float ex = 0.f;
    if (valid) {
      s = col_src[i];
      float a = al_srcH[s] + adn + edotH[i];
      a = (a > 0.f) ? a : 0.2f * a;
      ex = __expf(a);
    }
    denp += ex;

    const int cntc = min(64, end - base);
    auto issue = [&](int g, float4 (&v)[4], float (&w)[4]) {
#pragma unroll
      for (int u = 0; u < 4; ++u) {
        int tt = (g * 4 + u) * 4 + grp16;  // <= 63; overshoot lanes ex=0
        int sv = __shfl(s, tt);
        w[u] = __shfl(ex, tt);
        v[u] = *reinterpret_cast<const float4*>(hplane + (size_t)sv * 64 +
                                                sub * 4);
      }
    };
    auto fma4 = [&](float4 (&v)[4], float (&w)[4]) {
#pragma unroll
      for (int u = 0; u < 4; ++u) {
        acc4.x += w[u] * v[u].x; acc4.y += w[u] * v[u].y;
        acc4.z += w[u] * v[u].z; acc4.w += w[u] * v[u].w;
      }
    };
    const int nbat = (cntc + 15) >> 4;  // batches of 16 edges, <= 4
    float4 va[4], vb[4];
    float wa[4], wb[4];
    issue(0, va, wa);
    int g = 0;
    for (;;) {
      if (g + 1 < nbat) issue(g + 1, vb, wb);
      fma4(va, wa);
      if (++g >= nbat) break;
      if (g + 1 < nbat) issue(g + 1, va, wa);
      fma4(vb, wb);
      if (++g >= nbat) break;
    }
  }

  const float den = wave_sum64(denp);

  acc4.x += __shfl_xor(acc4.x, 16); acc4.x += __shfl_xor(acc4.x, 32);
  acc4.y += __shfl_xor(acc4.y, 16); acc4.y += __shfl_xor(acc4.y, 32);
  acc4.z += __shfl_xor(acc4.z, 16); acc4.z += __shfl_xor(acc4.z, 32);
  acc4.w += __shfl_xor(acc4.w, 16); acc4.w += __shfl_xor(acc4.w, 32);
  if (lane < 16) {
    float inv = 1.f / (den + 1e-16f);
    if (FIRST) {
      float4 o;
      o.x = acc4.x * inv; o.y = acc4.y * inv;
      o.z = acc4.z * inv; o.w = acc4.w * inv;
      *reinterpret_cast<float4*>(partial + (size_t)node * 64 + sub * 4) = o;
    } else {
      float4 p =
          *reinterpret_cast<const float4*>(partial + (size_t)node * 64 + sub * 4);
      float4 bv = *reinterpret_cast<const float4*>(bias + sub * 4);
      float4 o;
      o.x = fmaxf((p.x + acc4.x * inv) * 0.5f + bv.x, 0.f);
      o.y = fmaxf((p.y + acc4.y * inv) * 0.5f + bv.y, 0.f);
      o.z = fmaxf((p.z + acc4.z * inv) * 0.5f + bv.z, 0.f);
      o.w = fmaxf((p.w + acc4.w * inv) * 0.5f + bv.w, 0.f);
      *reinterpret_cast<float4*>(out + (size_t)node * 64 + sub * 4) = o;
    }
  }
}

// --------------------------- launch ----------------------------------------

static inline size_t align_up(size_t v, size_t a) { return (v + a - 1) & ~(a - 1); }

extern "C" void kernel_launch(void* const* d_in, const int* in_sizes, int n_in,
                              void* d_out, int out_size, void* d_ws,
                              size_t ws_size, hipStream_t stream) {
  const float* x = (const float*)d_in[0];
  const int* ei = (const int*)d_in[1];
  const float* ea = (const float*)d_in[2];

  const int N = in_sizes[0] / 64;
  const int E = in_sizes[1] / 2;
  const int* src0 = ei;
  const int* dst0 = ei + E;
  const int M = E + N;  // CSR slots

  const float* W[4] = {(const float*)d_in[3], (const float*)d_in[9],
                       (const float*)d_in[15], (const float*)d_in[21]};
  const float* As[4] = {(const float*)d_in[4], (const float*)d_in[10],
                        (const float*)d_in[16], (const float*)d_in[22]};
  const float* Ad[4] = {(const float*)d_in[5], (const float*)d_in[11],
                        (const float*)d_in[17], (const float*)d_in[23]};
  const float* We[4] = {(const float*)d_in[6], (const float*)d_in[12],
                        (const float*)d_in[18], (const float*)d_in[24]};
  const float* Ae[4] = {(const float*)d_in[7], (const float*)d_in[13],
                        (const float*)d_in[19], (const float*)d_in[25]};
  const float* B[4] = {(const float*)d_in[8], (const float*)d_in[14],
                       (const float*)d_in[20], (const float*)d_in[26]};

  // workspace carve-up
  char* p = (char*)d_ws;
  size_t off = 0;
  auto carve = [&](size_t bytes) {
    void* r = p + off;
    off = align_up(off + bytes, 256);
    return r;
  };
  const int NBK = (N + GSZ - 1) / GSZ;  // coarse buckets (196 for N=50000)
  int* cnt = (int*)carve((size_t)N * 4);
  int* row_ptr = (int*)carve((size_t)(N + 1) * 4);
  int* bsum = (int*)carve((size_t)256 * 4);
  int* bfill = (int*)carve((size_t)NBK * 4);
  int2* bbuf = (int2*)carve((size_t)NBK * CAPB * 8);  // reused as `partial`
  int* col_src = (int*)carve((size_t)M * 4);
  int* eid = (int*)carve((size_t)M * 4);
  float* comb = (float*)carve(256);
  float* edot0 = (float*)carve((size_t)M * 4);
  float* e1a = (float*)carve((size_t)M * 4);
  float* e1b = (float*)carve((size_t)M * 4);
  float* e2a = (float*)carve((size_t)M * 4);
  float* e2b = (float*)carve((size_t)M * 4);
  float* edot3 = (float*)carve((size_t)M * 4);
  float* al_src = (float*)carve((size_t)N * 2 * 4);
  float* al_dst = (float*)carve((size_t)N * 2 * 4);
  float* h_proj = (float*)carve((size_t)N * 128 * 4);
  float* buf_a = (float*)carve((size_t)N * 64 * 4);
  float* buf_b = (float*)carve((size_t)N * 64 * 4);
  float* partial = (float*)bbuf;  // 16 MB region, dead after CSR build; need 12.8
  (void)ws_size;

  const int nb = (N + 1023) / 1024;  // <=64 required (N<=65536)

  // ---- CSR + per-edge dots (graph is layer-invariant) ----
  hipMemsetAsync(bfill, 0, (size_t)NBK * 4, stream);
  bin_kernel<<<(E + CHUNK - 1) / CHUNK, 256, 0, stream>>>(src0, dst0, bfill,
                                                          bbuf, E);
  count_kernel<<<NBK, 256, 0, stream>>>(bfill, bbuf, cnt, N);
  scan1_kernel<<<nb, 256, 0, stream>>>(cnt, row_ptr, bsum, N);
  scan2_kernel<<<1, 64, 0, stream>>>(bsum, nb);
  scan3_kernel<<<(N + 255) / 256, 256, 0, stream>>>(row_ptr, bsum, N, nb);
  place_kernel<<<NBK, 256, 0, stream>>>(row_ptr, bfill, bbuf, col_src, eid, N,
                                        E);
  comb_all_kernel<<<1, 64, 0, stream>>>(We[0], Ae[0], We[1], Ae[1], We[2],
                                        Ae[2], We[3], Ae[3], comb);
  edge_prep2_kernel<<<(N + NPB - 1) / NPB, 256, 0, stream>>>(
      row_ptr, eid, ea, comb, edot0, e1a, e1b, e2a, e2b, edot3, N, E);

  const int gemm_grid = (N + 31) / 32;
  const int node_grid = (N + 3) / 4;
  const size_t plane = (size_t)N * 64;

  // ---- layer 0: in64 -> H1,C64, concat, relu ----
  gemm_proj_kernel<64, 1><<<gemm_grid, 256, 0, stream>>>(
      x, W[0], As[0], Ad[0], h_proj, al_src, al_dst, N);
  gat_node_kernel<64, true><<<node_grid, 256, 0, stream>>>(
      row_ptr, col_src, edot0, h_proj, al_src, al_dst, B[0], buf_a, N);

  // ---- layer 1: 64 -> H2,C64, mean, relu (two per-head passes) ----
  gemm_proj_kernel<128, 2><<<gemm_grid, 256, 0, stream>>>(
      buf_a, W[1], As[1], Ad[1], h_proj, al_src, al_dst, N);
  gat_head_kernel<true><<<node_grid, 256, 0, stream>>>(
      row_ptr, col_src, e1a, h_proj, al_src, al_dst, B[1], partial, nullptr, N);
  gat_head_kernel<false><<<node_grid, 256, 0, stream>>>(
      row_ptr, col_src, e1b, h_proj + plane, al_src + N, al_dst + N, B[1],
      partial, buf_b, N);

  // ---- layer 2: 64 -> H2,C64, mean, relu (two per-head passes) ----
  gemm_proj_kernel<128, 2><<<gemm_grid, 256, 0, stream>>>(
      buf_b, W[2], As[2], Ad[2], h_proj, al_src, al_dst, N);
  gat_head_kernel<true><<<node_grid, 256, 0, stream>>>(
      row_ptr, col_src, e2a, h_proj, al_src, al_dst, B[2], partial, nullptr, N);
  gat_head_kernel<false><<<node_grid, 256, 0, stream>>>(
      row_ptr, col_src, e2b, h_proj + plane, al_src + N, al_dst + N, B[2],
      partial, buf_a, N);

  // ---- layer 3: 64 -> H1,C2, concat, no relu ----
  gemm_proj_kernel<2, 1><<<gemm_grid, 256, 0, stream>>>(
      buf_a, W[3], As[3], Ad[3], h_proj, al_src, al_dst, N);
  gat_node_kernel<2, false><<<node_grid, 256, 0, stream>>>(
      row_ptr, col_src, edot3, h_proj, al_src, al_dst, B[3], (float*)d_out, N);
}

// Round 12
// 491.347 us; speedup vs baseline: 1.0714x; 1.0714x over previous
//
#include <hip/hip_runtime.h>
#include <math.h>

// ---------------------------------------------------------------------------
// GAT network: 4 layers, N=50000 nodes, E=1.6M edges, edge_dim=8.
// CSR build (all global writes coalesced): bin -> count -> scan -> place.
// Edge dots: flat slot-dense kernel (grid-stride, full occupancy) + wave-per-
// node self-mean kernel (self dot = row mean of edge dots, by linearity).
// H=2 layers: two per-head passes over head-major planes; ping-pong gathers.
// ---------------------------------------------------------------------------

#define GSZ 256      // nodes per coarse bucket (bucket = dst>>8)
#define CAPB 10240   // per-bucket region capacity (avg fill 8192, 22 sigma)
#define CHUNK 4096   // edges per bin block
#define CAP_C 9984   // place stage capacity (avg span 8448, 17 sigma)

__device__ __forceinline__ float wave_sum64(float v) {
#pragma unroll
  for (int o = 32; o >= 1; o >>= 1) v += __shfl_xor(v, o);
  return v;
}
__device__ __forceinline__ float dot8(const float4& a, const float4& b,
                                      const float* c) {
  return a.x * c[0] + a.y * c[1] + a.z * c[2] + a.w * c[3] + b.x * c[4] +
         b.y * c[5] + b.z * c[6] + b.w * c[7];
}

// --------------------------- CSR build ------------------------------------

__global__ __launch_bounds__(256) void bin_kernel(const int* __restrict__ src,
                                                  const int* __restrict__ dst,
                                                  int* __restrict__ bfill,
                                                  int2* __restrict__ bbuf,
                                                  int E_) {
  __shared__ int histo[256];
  __shared__ int scanb[256];
  __shared__ int segstart[256];
  __shared__ int gbase[256];
  __shared__ int cur[256];
  __shared__ int2 stage[CHUNK];
  __shared__ int gtarg[CHUNK];
  const int t = threadIdx.x;
  const int e0 = blockIdx.x * CHUNK;
  const int cnt = min(CHUNK, E_ - e0);
  histo[t] = 0;
  __syncthreads();
  int myd[CHUNK / 256];
#pragma unroll
  for (int k = 0; k < CHUNK / 256; ++k) {
    int i = t + k * 256;
    int d = -1;
    if (i < cnt) {
      d = dst[e0 + i];
      atomicAdd(&histo[d >> 8], 1);
    }
    myd[k] = d;
  }
  __syncthreads();
  const int v = histo[t];
  int acc = v;
  scanb[t] = v;
  __syncthreads();
#pragma unroll
  for (int o = 1; o < 256; o <<= 1) {
    int u = (t >= o) ? scanb[t - o] : 0;
    __syncthreads();
    acc += u;
    scanb[t] = acc;
    __syncthreads();
  }
  int gp = 0;
  if (v > 0) gp = atomicAdd(&bfill[t], v);  // t = bucket id
  segstart[t] = acc - v;                    // exclusive
  gbase[t] = t * CAPB + min(gp, CAPB - v);  // clamp (never triggers)
  cur[t] = 0;
  __syncthreads();
#pragma unroll
  for (int k = 0; k < CHUNK / 256; ++k) {
    int i = t + k * 256;
    int d = myd[k];
    if (d >= 0) {
      int b = d >> 8;
      int s = src[e0 + i];
      int p = atomicAdd(&cur[b], 1);
      int sl = segstart[b] + p;
      stage[sl] = make_int2(s, (e0 + i) | ((d & 255) << 21));
      gtarg[sl] = gbase[b] + p;
    }
  }
  __syncthreads();
  for (int i = t; i < cnt; i += 256) bbuf[gtarg[i]] = stage[i];
}

__global__ __launch_bounds__(256) void count_kernel(
    const int* __restrict__ bfill, const int2* __restrict__ bbuf,
    int* __restrict__ cnt, int n) {
  __shared__ int h[256];
  const int b = blockIdx.x;
  const int t = threadIdx.x;
  h[t] = 0;
  __syncthreads();
  const int m = min(bfill[b], CAPB);
  const int2* reg = bbuf + (size_t)b * CAPB;
  for (int i = t; i < m; i += 256) {
    int dl = ((unsigned)reg[i].y) >> 21;
    atomicAdd(&h[dl], 1);
  }
  __syncthreads();
  int node = b * GSZ + t;
  if (node < n) cnt[node] = h[t];
}

__global__ __launch_bounds__(256) void scan1_kernel(const int* __restrict__ cnt,
                                                    int* __restrict__ rowp,
                                                    int* __restrict__ bsum,
                                                    int n) {
  __shared__ int sd[256];
  const int t = threadIdx.x;
  const int base = blockIdx.x * 1024 + t * 4;
  int v0 = (base + 0 < n) ? cnt[base + 0] + 1 : 0;
  int v1 = (base + 1 < n) ? cnt[base + 1] + 1 : 0;
  int v2 = (base + 2 < n) ? cnt[base + 2] + 1 : 0;
  int v3 = (base + 3 < n) ? cnt[base + 3] + 1 : 0;
  const int s = v0 + v1 + v2 + v3;
  sd[t] = s;
  __syncthreads();
  int acc = s;
#pragma unroll
  for (int o = 1; o < 256; o <<= 1) {
    int u = (t >= o) ? sd[t - o] : 0;
    __syncthreads();
    acc += u;
    sd[t] = acc;
    __syncthreads();
  }
  int excl = acc - s;
  if (base + 0 < n) rowp[base + 0] = excl;
  if (base + 1 < n) rowp[base + 1] = excl + v0;
  if (base + 2 < n) rowp[base + 2] = excl + v0 + v1;
  if (base + 3 < n) rowp[base + 3] = excl + v0 + v1 + v2;
  if (t == 255) bsum[blockIdx.x] = acc;
}

__global__ void scan2_kernel(int* __restrict__ bsum, int nb) {
  const int lane = threadIdx.x;
  int v = (lane < nb) ? bsum[lane] : 0;
  int incl = v;
#pragma unroll
  for (int o = 1; o < 64; o <<= 1) {
    int u = __shfl_up(incl, o);
    if (lane >= o) incl += u;
  }
  if (lane < nb) bsum[lane] = incl - v;
  if (lane == 63) bsum[nb] = incl;
}

__global__ void scan3_kernel(int* __restrict__ rowp,
                             const int* __restrict__ bsum, int n, int nb) {
  int i = blockIdx.x * 256 + threadIdx.x;
  if (i >= n) return;
  rowp[i] += bsum[i >> 10];
  if (i == 0) rowp[n] = bsum[nb];
}

__global__ __launch_bounds__(256) void place_kernel(
    const int* __restrict__ rowp, const int* __restrict__ bfill,
    const int2* __restrict__ bbuf, int* __restrict__ col_src,
    int* __restrict__ eidA, int n, int E_) {
  __shared__ int rp[GSZ + 1];
  __shared__ int cur[GSZ];
  __shared__ int2 stage[CAP_C];
  const int b = blockIdx.x;
  const int t = threadIdx.x;
  const int lo = b * GSZ;
  const int nk = min(GSZ, n - lo);
  for (int i = t; i <= nk; i += 256) rp[i] = rowp[lo + i];  // covers rp[256]!
  cur[t] = 0;
  __syncthreads();
  const int s0 = rp[0];
  const int span = rp[nk] - s0;
  const bool fits = (span <= CAP_C);
  const int m = min(bfill[b], CAPB);
  const int2* reg = bbuf + (size_t)b * CAPB;
  for (int i = t; i < m; i += 256) {
    int2 pl = reg[i];
    int dl = ((unsigned)pl.y) >> 21;
    int e2 = pl.y & 0x1FFFFF;
    int p = atomicAdd(&cur[dl], 1);
    int slot = rp[dl] + p;
    if (fits) stage[slot - s0] = make_int2(pl.x, e2);
    else { col_src[slot] = pl.x; eidA[slot] = e2; }
  }
  if (t < nk) {  // self entry: last slot of each row
    int slot = rp[t + 1] - 1;
    int node = lo + t;
    if (fits) stage[slot - s0] = make_int2(node, E_ + node);
    else { col_src[slot] = node; eidA[slot] = E_ + node; }
  }
  __syncthreads();
  if (fits) {
    for (int i = t; i < span; i += 256) {
      int2 v = stage[i];
      col_src[s0 + i] = v.x;
      eidA[s0 + i] = v.y;
    }
  }
}

// --------------------------- comb (all layers) ------------------------------
__global__ void comb_all_kernel(const float* __restrict__ We0,
                                const float* __restrict__ ae0,
                                const float* __restrict__ We1,
                                const float* __restrict__ ae1,
                                const float* __restrict__ We2,
                                const float* __restrict__ ae2,
                                const float* __restrict__ We3,
                                const float* __restrict__ ae3,
                                float* __restrict__ comb) {
  int t = threadIdx.x;
  if (t >= 48) return;
  float s = 0.f;
  if (t < 8) {
    int d = t;
    for (int c = 0; c < 64; ++c) s += We0[d * 64 + c] * ae0[c];
  } else if (t < 24) {
    int idx = t - 8, h = idx >> 3, d = idx & 7;
    for (int c = 0; c < 64; ++c) s += We1[d * 128 + h * 64 + c] * ae1[h * 64 + c];
  } else if (t < 40) {
    int idx = t - 24, h = idx >> 3, d = idx & 7;
    for (int c = 0; c < 64; ++c) s += We2[d * 128 + h * 64 + c] * ae2[h * 64 + c];
  } else {
    int d = t - 40;
    for (int c = 0; c < 2; ++c) s += We3[d * 2 + c] * ae3[c];
  }
  comb[t] = s;
}

// --------------------------- edge dots (flat, slot-dense) -------------------
// Grid-stride over all M CSR slots; every lane busy; coalesced plane writes.
__global__ __launch_bounds__(256) void edge_dots_kernel(
    const int* __restrict__ eid, const float* __restrict__ ea,
    const float* __restrict__ comb, float* __restrict__ edot0,
    float* __restrict__ e1a, float* __restrict__ e1b,
    float* __restrict__ e2a, float* __restrict__ e2b,
    float* __restrict__ edot3, int M_, int E_) {
  __shared__ float cb[48];
  if (threadIdx.x < 48) cb[threadIdx.x] = comb[threadIdx.x];
  __syncthreads();
  const int stride = gridDim.x * 256;
  for (int i = blockIdx.x * 256 + threadIdx.x; i < M_; i += stride) {
    int e = eid[i];
    if (e < E_) {
      const float4* p = reinterpret_cast<const float4*>(ea + (size_t)e * 8);
      float4 a = p[0], b = p[1];
      edot0[i] = dot8(a, b, cb + 0);
      e1a[i] = dot8(a, b, cb + 8);
      e1b[i] = dot8(a, b, cb + 16);
      e2a[i] = dot8(a, b, cb + 24);
      e2b[i] = dot8(a, b, cb + 32);
      edot3[i] = dot8(a, b, cb + 40);
    }
  }
}

// --------------------------- self mean (wave per node) ----------------------
// Self-slot dot = mean of the row's edge dots (dot is linear in the attr).
__global__ __launch_bounds__(256) void self_mean_kernel(
    const int* __restrict__ rowp, float* __restrict__ edot0,
    float* __restrict__ e1a, float* __restrict__ e1b,
    float* __restrict__ e2a, float* __restrict__ e2b,
    float* __restrict__ edot3, int n) {
  const int lane = threadIdx.x & 63;
  const int node = blockIdx.x * 4 + (threadIdx.x >> 6);
  if (node >= n) return;
  const int a = rowp[node];
  const int b = rowp[node + 1] - 1;  // self slot
  float s0 = 0.f, s1 = 0.f, s2 = 0.f, s3 = 0.f, s4 = 0.f, s5 = 0.f;
  for (int j = a + lane; j < b; j += 64) {
    s0 += edot0[j]; s1 += e1a[j]; s2 += e1b[j];
    s3 += e2a[j]; s4 += e2b[j]; s5 += edot3[j];
  }
  s0 = wave_sum64(s0); s1 = wave_sum64(s1); s2 = wave_sum64(s2);
  s3 = wave_sum64(s3); s4 = wave_sum64(s4); s5 = wave_sum64(s5);
  if (lane == 0) {
    float inv = 1.f / fmaxf((float)(b - a), 1.f);
    edot0[b] = s0 * inv; e1a[b] = s1 * inv; e1b[b] = s2 * inv;
    e2a[b] = s3 * inv; e2b[b] = s4 * inv; edot3[b] = s5 * inv;
  }
}

// --------------------------- projection GEMM -------------------------------
// h = x @ W; H==2: head-major planes h + h*n*64. al_src/al_dst head-major
// [h][n] (H==1 indexing degenerates to [n]).
template <int HC, int H>
__global__ __launch_bounds__(256) void gemm_proj_kernel(
    const float* __restrict__ x, const float* __restrict__ W,
    const float* __restrict__ a_src, const float* __restrict__ a_dst,
    float* __restrict__ h, float* __restrict__ al_src,
    float* __restrict__ al_dst, int n) {
  constexpr int IN = 64;
  constexpr int C = HC / H;
  __shared__ float xs[32][IN];
  const int tid = threadIdx.x;
  const int j = tid % HC;
  const int rsub = tid / HC;
  constexpr int RPP = 256 / HC > 0 ? 256 / HC : 1;

  float wr[IN];
#pragma unroll
  for (int k = 0; k < IN; ++k) wr[k] = W[k * HC + j];
  const float asj = a_src[j];
  const float adj = a_dst[j];

  const int row0 = blockIdx.x * 32;
  {
    const float4* xv = reinterpret_cast<const float4*>(x);
    float4* xsv = reinterpret_cast<float4*>(&xs[0][0]);
    for (int i = tid; i < 32 * IN / 4; i += 256) {
      int r = i / (IN / 4);
      int row = row0 + r;
      float4 v = make_float4(0.f, 0.f, 0.f, 0.f);
      if (row < n) v = xv[(size_t)row * (IN / 4) + (i % (IN / 4))];
      xsv[i] = v;
    }
  }
  __syncthreads();

  for (int rb = 0; rb < 32; rb += RPP) {
    int r = rb + rsub;
    if (r >= 32) break;  // wave-uniform (only for HC=2 tails)
    int row = row0 + r;
    float acc = 0.f;
#pragma unroll
    for (int k4 = 0; k4 < IN / 4; ++k4) {
      float4 xv = *reinterpret_cast<const float4*>(&xs[r][k4 * 4]);
      acc += xv.x * wr[k4 * 4 + 0] + xv.y * wr[k4 * 4 + 1] +
             xv.z * wr[k4 * 4 + 2] + xv.w * wr[k4 * 4 + 3];
    }
    if (row < n) {
      size_t oidx = (H == 2)
                        ? ((size_t)(j >> 6) * ((size_t)n * 64) +
                           (size_t)row * 64 + (j & 63))
                        : ((size_t)row * HC + j);
      h[oidx] = acc;
    }
    float ps = acc * asj;
    float pd = acc * adj;
#pragma unroll
    for (int o = C / 2; o >= 1; o >>= 1) {
      ps += __shfl_xor(ps, o);
      pd += __shfl_xor(pd, o);
    }
    if (row < n && (j % C) == 0) {
      int hh = j / C;
      al_src[(size_t)hh * n + row] = ps;
      al_dst[(size_t)hh * n + row] = pd;
    }
  }
}

// ------------------- fused node kernel (H=1 layers) -------------------------
template <int C, bool RELU>
__global__ __launch_bounds__(256) void gat_node_kernel(
    const int* __restrict__ row_ptr, const int* __restrict__ col_src,
    const float* __restrict__ edot, const float* __restrict__ h_proj,
    const float* __restrict__ al_src, const float* __restrict__ al_dst,
    const float* __restrict__ bias, float* __restrict__ out, int n) {
  const int lane = threadIdx.x & 63;
  const int node = blockIdx.x * 4 + (threadIdx.x >> 6);
  if (node >= n) return;

  const float adn = al_dst[node];
  const int start = row_ptr[node];
  const int end = row_ptr[node + 1];

  float denp = 0.f;
  float4 acc4 = make_float4(0.f, 0.f, 0.f, 0.f);
  float accp = 0.f;  // C==2 path accumulator

  const int sub = lane & 15;    // channel quad
  const int grp16 = lane >> 4;  // edge slot within group-of-4

  for (int base = start; base < end; base += 64) {
    const int i = base + lane;
    const bool valid = (i < end);
    int s = 0;
    float ex = 0.f;
    if (valid) {
      s = col_src[i];
      float a = al_src[s] + adn + edot[i];
      a = (a > 0.f) ? a : 0.2f * a;
      ex = __expf(a);
    }
    denp += ex;

    const int cntc = min(64, end - base);
    if (C == 2) {
      const int half = lane >> 1;
      const int ch = lane & 1;
#pragma unroll
      for (int sb = 0; sb < 2; ++sb) {
        int tt = sb * 32 + half;
        int sv = __shfl(s, tt);
        float w = __shfl(ex, tt);
        if (tt < cntc) accp += w * h_proj[sv * 2 + ch];
      }
    } else {
      // register ping-pong: two 4-load batches in flight
      auto issue = [&](int g, float4 (&v)[4], float (&w)[4]) {
#pragma unroll
        for (int u = 0; u < 4; ++u) {
          int tt = (g * 4 + u) * 4 + grp16;  // <= 63; overshoot lanes ex=0
          int sv = __shfl(s, tt);
          w[u] = __shfl(ex, tt);
          v[u] = *reinterpret_cast<const float4*>(h_proj + (size_t)sv * 64 +
                                                  sub * 4);
        }
      };
      auto fma4 = [&](float4 (&v)[4], float (&w)[4]) {
#pragma unroll
        for (int u = 0; u < 4; ++u) {
          acc4.x += w[u] * v[u].x; acc4.y += w[u] * v[u].y;
          acc4.z += w[u] * v[u].z; acc4.w += w[u] * v[u].w;
        }
      };
      const int nbat = (cntc + 15) >> 4;  // batches of 16 edges, <= 4
      float4 va[4], vb[4];
      float wa[4], wb[4];
      issue(0, va, wa);
      int g = 0;
      for (;;) {
        if (g + 1 < nbat) issue(g + 1, vb, wb);
        fma4(va, wa);
        if (++g >= nbat) break;
        if (g + 1 < nbat) issue(g + 1, va, wa);
        fma4(vb, wb);
        if (++g >= nbat) break;
      }
    }
  }

  const float den = wave_sum64(denp);

  if (C == 2) {
#pragma unroll
    for (int o = 2; o <= 32; o <<= 1) accp += __shfl_xor(accp, o);
    if (lane < 2) {
      float v = accp / (den + 1e-16f) + bias[lane];
      if (RELU) v = fmaxf(v, 0.f);
      out[node * 2 + lane] = v;
    }
  } else {
    acc4.x += __shfl_xor(acc4.x, 16); acc4.x += __shfl_xor(acc4.x, 32);
    acc4.y += __shfl_xor(acc4.y, 16); acc4.y += __shfl_xor(acc4.y, 32);
    acc4.z += __shfl_xor(acc4.z, 16); acc4.z += __shfl_xor(acc4.z, 32);
    acc4.w += __shfl_xor(acc4.w, 16); acc4.w += __shfl_xor(acc4.w, 32);
    if (lane < 16) {
      float inv = 1.f / (den + 1e-16f);
      float4 bv = *reinterpret_cast<const float4*>(bias + sub * 4);
      float4 o;
      o.x = acc4.x * inv + bv.x; o.y = acc4.y * inv + bv.y;
      o.z = acc4.z * inv + bv.z; o.w = acc4.w * inv + bv.w;
      if (RELU) {
        o.x = fmaxf(o.x, 0.f); o.y = fmaxf(o.y, 0.f);
        o.z = fmaxf(o.z, 0.f); o.w = fmaxf(o.w, 0.f);
      }
      *reinterpret_cast<float4*>(out + (size_t)node * 64 + sub * 4) = o;
    }
  }
}

// ------------------- per-head pass kernel (H=2 layers) ----------------------
template <bool FIRST>
__global__ __launch_bounds__(256) void gat_head_kernel(
    const int* __restrict__ row_ptr, const int* __restrict__ col_src,
    const float* __restrict__ edotH, const float* __restrict__ hplane,
    const float* __restrict__ al_srcH, const float* __restrict__ al_dstH,
    const float* __restrict__ bias, float* __restrict__ partial,
    float* __restrict__ out, int n) {
  const int lane = threadIdx.x & 63;
  const int node = blockIdx.x * 4 + (threadIdx.x >> 6);
  if (node >= n) return;

  const float adn = al_dstH[node];
  const int start = row_ptr[node];
  const int end = row_ptr[node + 1];

  float denp = 0.f;
  float4 acc4 = make_float4(0.f, 0.f, 0.f, 0.f);

  const int sub = lane & 15;
  const int grp16 = lane >> 4;

  for (int base = start; base < end; base += 64) {
    const int i = base + lane;
    const bool valid = (i < end);
    int s = 0;
    float ex = 0.f;
    if (valid) {
      s = col_src[i];
      float a = al_srcH[s] + adn + edotH[i];
      a = (a > 0.f) ? a : 0.2f * a;
      ex = __expf(a);
    }
    denp += ex;

    const int cntc = min(64, end - base);
    auto issue = [&](int g, float4 (&v)[4], float (&w)[4]) {
#pragma unroll
      for (int u = 0; u < 4; ++u) {
        int tt = (g * 4 + u) * 4 + grp16;  // <= 63; overshoot lanes ex=0
        int sv = __shfl(s, tt);
        w[u] = __shfl(ex, tt);
        v[u] = *reinterpret_cast<const float4*>(hplane + (size_t)sv * 64 +
                                                sub * 4);
      }
    };
    auto fma4 = [&](float4 (&v)[4], float (&w)[4]) {
#pragma unroll
      for (int u = 0; u < 4; ++u) {
        acc4.x += w[u] * v[u].x; acc4.y += w[u] * v[u].y;
        acc4.z += w[u] * v[u].z; acc4.w += w[u] * v[u].w;
      }
    };
    const int nbat = (cntc + 15) >> 4;  // batches of 16 edges, <= 4
    float4 va[4], vb[4];
    float wa[4], wb[4];
    issue(0, va, wa);
    int g = 0;
    for (;;) {
      if (g + 1 < nbat) issue(g + 1, vb, wb);
      fma4(va, wa);
      if (++g >= nbat) break;
      if (g + 1 < nbat) issue(g + 1, va, wa);
      fma4(vb, wb);
      if (++g >= nbat) break;
    }
  }

  const float den = wave_sum64(denp);

  acc4.x += __shfl_xor(acc4.x, 16); acc4.x += __shfl_xor(acc4.x, 32);
  acc4.y += __shfl_xor(acc4.y, 16); acc4.y += __shfl_xor(acc4.y, 32);
  acc4.z += __shfl_xor(acc4.z, 16); acc4.z += __shfl_xor(acc4.z, 32);
  acc4.w += __shfl_xor(acc4.w, 16); acc4.w += __shfl_xor(acc4.w, 32);
  if (lane < 16) {
    float inv = 1.f / (den + 1e-16f);
    if (FIRST) {
      float4 o;
      o.x = acc4.x * inv; o.y = acc4.y * inv;
      o.z = acc4.z * inv; o.w = acc4.w * inv;
      *reinterpret_cast<float4*>(partial + (size_t)node * 64 + sub * 4) = o;
    } else {
      float4 p =
          *reinterpret_cast<const float4*>(partial + (size_t)node * 64 + sub * 4);
      float4 bv = *reinterpret_cast<const float4*>(bias + sub * 4);
      float4 o;
      o.x = fmaxf((p.x + acc4.x * inv) * 0.5f + bv.x, 0.f);
      o.y = fmaxf((p.y + acc4.y * inv) * 0.5f + bv.y, 0.f);
      o.z = fmaxf((p.z + acc4.z * inv) * 0.5f + bv.z, 0.f);
      o.w = fmaxf((p.w + acc4.w * inv) * 0.5f + bv.w, 0.f);
      *reinterpret_cast<float4*>(out + (size_t)node * 64 + sub * 4) = o;
    }
  }
}

// --------------------------- launch ----------------------------------------

static inline size_t align_up(size_t v, size_t a) { return (v + a - 1) & ~(a - 1); }

extern "C" void kernel_launch(void* const* d_in, const int* in_sizes, int n_in,
                              void* d_out, int out_size, void* d_ws,
                              size_t ws_size, hipStream_t stream) {
  const float* x = (const float*)d_in[0];
  const int* ei = (const int*)d_in[1];
  const float* ea = (const float*)d_in[2];

  const int N = in_sizes[0] / 64;
  const int E = in_sizes[1] / 2;
  const int* src0 = ei;
  const int* dst0 = ei + E;
  const int M = E + N;  // CSR slots

  const float* W[4] = {(const float*)d_in[3], (const float*)d_in[9],
                       (const float*)d_in[15], (const float*)d_in[21]};
  const float* As[4] = {(const float*)d_in[4], (const float*)d_in[10],
                        (const float*)d_in[16], (const float*)d_in[22]};
  const float* Ad[4] = {(const float*)d_in[5], (const float*)d_in[11],
                        (const float*)d_in[17], (const float*)d_in[23]};
  const float* We[4] = {(const float*)d_in[6], (const float*)d_in[12],
                        (const float*)d_in[18], (const float*)d_in[24]};
  const float* Ae[4] = {(const float*)d_in[7], (const float*)d_in[13],
                        (const float*)d_in[19], (const float*)d_in[25]};
  const float* B[4] = {(const float*)d_in[8], (const float*)d_in[14],
                       (const float*)d_in[20], (const float*)d_in[26]};

  // workspace carve-up
  char* p = (char*)d_ws;
  size_t off = 0;
  auto carve = [&](size_t bytes) {
    void* r = p + off;
    off = align_up(off + bytes, 256);
    return r;
  };
  const int NBK = (N + GSZ - 1) / GSZ;  // coarse buckets (196 for N=50000)
  int* cnt = (int*)carve((size_t)N * 4);
  int* row_ptr = (int*)carve((size_t)(N + 1) * 4);
  int* bsum = (int*)carve((size_t)256 * 4);
  int* bfill = (int*)carve((size_t)NBK * 4);
  int2* bbuf = (int2*)carve((size_t)NBK * CAPB * 8);  // reused as `partial`
  int* col_src = (int*)carve((size_t)M * 4);
  int* eid = (int*)carve((size_t)M * 4);
  float* comb = (float*)carve(256);
  float* edot0 = (float*)carve((size_t)M * 4);
  float* e1a = (float*)carve((size_t)M * 4);
  float* e1b = (float*)carve((size_t)M * 4);
  float* e2a = (float*)carve((size_t)M * 4);
  float* e2b = (float*)carve((size_t)M * 4);
  float* edot3 = (float*)carve((size_t)M * 4);
  float* al_src = (float*)carve((size_t)N * 2 * 4);
  float* al_dst = (float*)carve((size_t)N * 2 * 4);
  float* h_proj = (float*)carve((size_t)N * 128 * 4);
  float* buf_a = (float*)carve((size_t)N * 64 * 4);
  float* buf_b = (float*)carve((size_t)N * 64 * 4);
  float* partial = (float*)bbuf;  // 16 MB region, dead after CSR build; need 12.8
  (void)ws_size;

  const int nb = (N + 1023) / 1024;  // <=64 required (N<=65536)

  // ---- CSR + per-edge dots (graph is layer-invariant) ----
  hipMemsetAsync(bfill, 0, (size_t)NBK * 4, stream);
  bin_kernel<<<(E + CHUNK - 1) / CHUNK, 256, 0, stream>>>(src0, dst0, bfill,
                                                          bbuf, E);
  count_kernel<<<NBK, 256, 0, stream>>>(bfill, bbuf, cnt, N);
  scan1_kernel<<<nb, 256, 0, stream>>>(cnt, row_ptr, bsum, N);
  scan2_kernel<<<1, 64, 0, stream>>>(bsum, nb);
  scan3_kernel<<<(N + 255) / 256, 256, 0, stream>>>(row_ptr, bsum, N, nb);
  place_kernel<<<NBK, 256, 0, stream>>>(row_ptr, bfill, bbuf, col_src, eid, N,
                                        E);
  comb_all_kernel<<<1, 64, 0, stream>>>(We[0], Ae[0], We[1], Ae[1], We[2],
                                        Ae[2], We[3], Ae[3], comb);
  edge_dots_kernel<<<2048, 256, 0, stream>>>(eid, ea, comb, edot0, e1a, e1b,
                                             e2a, e2b, edot3, M, E);
  self_mean_kernel<<<(N + 3) / 4, 256, 0, stream>>>(row_ptr, edot0, e1a, e1b,
                                                    e2a, e2b, edot3, N);

  const int gemm_grid = (N + 31) / 32;
  const int node_grid = (N + 3) / 4;
  const size_t plane = (size_t)N * 64;

  // ---- layer 0: in64 -> H1,C64, concat, relu ----
  gemm_proj_kernel<64, 1><<<gemm_grid, 256, 0, stream>>>(
      x, W[0], As[0], Ad[0], h_proj, al_src, al_dst, N);
  gat_node_kernel<64, true><<<node_grid, 256, 0, stream>>>(
      row_ptr, col_src, edot0, h_proj, al_src, al_dst, B[0], buf_a, N);

  // ---- layer 1: 64 -> H2,C64, mean, relu (two per-head passes) ----
  gemm_proj_kernel<128, 2><<<gemm_grid, 256, 0, stream>>>(
      buf_a, W[1], As[1], Ad[1], h_proj, al_src, al_dst, N);
  gat_head_kernel<true><<<node_grid, 256, 0, stream>>>(
      row_ptr, col_src, e1a, h_proj, al_src, al_dst, B[1], partial, nullptr, N);
  gat_head_kernel<false><<<node_grid, 256, 0, stream>>>(
      row_ptr, col_src, e1b, h_proj + plane, al_src + N, al_dst + N, B[1],
      partial, buf_b, N);

  // ---- layer 2: 64 -> H2,C64, mean, relu (two per-head passes) ----
  gemm_proj_kernel<128, 2><<<gemm_grid, 256, 0, stream>>>(
      buf_b, W[2], As[2], Ad[2], h_proj, al_src, al_dst, N);
  gat_head_kernel<true><<<node_grid, 256, 0, stream>>>(
      row_ptr, col_src, e2a, h_proj, al_src, al_dst, B[2], partial, nullptr, N);
  gat_head_kernel<false><<<node_grid, 256, 0, stream>>>(
      row_ptr, col_src, e2b, h_proj + plane, al_src + N, al_dst + N, B[2],
      partial, buf_a, N);

  // ---- layer 3: 64 -> H1,C2, concat, no relu ----
  gemm_proj_kernel<2, 1><<<gemm_grid, 256, 0, stream>>>(
      buf_a, W[3], As[3], Ad[3], h_proj, al_src, al_dst, N);
  gat_node_kernel<2, false><<<node_grid, 256, 0, stream>>>(
      row_ptr, col_src, edot3, h_proj, al_src, al_dst, B[3], (float*)d_out, N);
}

// Round 13
// 475.212 us; speedup vs baseline: 1.1078x; 1.0340x over previous
//
#include <hip/hip_runtime.h>
#include <math.h>

// ---------------------------------------------------------------------------
// GAT network: 4 layers, N=50000 nodes, E=1.6M edges, edge_dim=8.
// CSR build (all global writes coalesced): bin -> count -> scan -> place.
// H=2 layers: two per-head passes over head-major h_proj planes; per-head
// edot planes; head-major al_src/al_dst. Gather loop: register ping-pong
// double buffer (two 4-load batches in flight).
// This is the round-10 configuration (best measured: 475.9 us).
// ---------------------------------------------------------------------------

#define GSZ 256      // nodes per coarse bucket (bucket = dst>>8)
#define CAPB 10240   // per-bucket region capacity (avg fill 8192, 22 sigma)
#define CHUNK 4096   // edges per bin block
#define CAP_C 9984   // place stage capacity (avg span 8448, 17 sigma)

__device__ __forceinline__ float wave_sum64(float v) {
#pragma unroll
  for (int o = 32; o >= 1; o >>= 1) v += __shfl_xor(v, o);
  return v;
}
__device__ __forceinline__ float dot8(const float4& a, const float4& b,
                                      const float* c) {
  return a.x * c[0] + a.y * c[1] + a.z * c[2] + a.w * c[3] + b.x * c[4] +
         b.y * c[5] + b.z * c[6] + b.w * c[7];
}

// --------------------------- CSR build ------------------------------------

__global__ __launch_bounds__(256) void bin_kernel(const int* __restrict__ src,
                                                  const int* __restrict__ dst,
                                                  int* __restrict__ bfill,
                                                  int2* __restrict__ bbuf,
                                                  int E_) {
  __shared__ int histo[256];
  __shared__ int scanb[256];
  __shared__ int segstart[256];
  __shared__ int gbase[256];
  __shared__ int cur[256];
  __shared__ int2 stage[CHUNK];
  __shared__ int gtarg[CHUNK];
  const int t = threadIdx.x;
  const int e0 = blockIdx.x * CHUNK;
  const int cnt = min(CHUNK, E_ - e0);
  histo[t] = 0;
  __syncthreads();
  int myd[CHUNK / 256];
#pragma unroll
  for (int k = 0; k < CHUNK / 256; ++k) {
    int i = t + k * 256;
    int d = -1;
    if (i < cnt) {
      d = dst[e0 + i];
      atomicAdd(&histo[d >> 8], 1);
    }
    myd[k] = d;
  }
  __syncthreads();
  const int v = histo[t];
  int acc = v;
  scanb[t] = v;
  __syncthreads();
#pragma unroll
  for (int o = 1; o < 256; o <<= 1) {
    int u = (t >= o) ? scanb[t - o] : 0;
    __syncthreads();
    acc += u;
    scanb[t] = acc;
    __syncthreads();
  }
  int gp = 0;
  if (v > 0) gp = atomicAdd(&bfill[t], v);  // t = bucket id
  segstart[t] = acc - v;                    // exclusive
  gbase[t] = t * CAPB + min(gp, CAPB - v);  // clamp (never triggers)
  cur[t] = 0;
  __syncthreads();
#pragma unroll
  for (int k = 0; k < CHUNK / 256; ++k) {
    int i = t + k * 256;
    int d = myd[k];
    if (d >= 0) {
      int b = d >> 8;
      int s = src[e0 + i];
      int p = atomicAdd(&cur[b], 1);
      int sl = segstart[b] + p;
      stage[sl] = make_int2(s, (e0 + i) | ((d & 255) << 21));
      gtarg[sl] = gbase[b] + p;
    }
  }
  __syncthreads();
  for (int i = t; i < cnt; i += 256) bbuf[gtarg[i]] = stage[i];
}

__global__ __launch_bounds__(256) void count_kernel(
    const int* __restrict__ bfill, const int2* __restrict__ bbuf,
    int* __restrict__ cnt, int n) {
  __shared__ int h[256];
  const int b = blockIdx.x;
  const int t = threadIdx.x;
  h[t] = 0;
  __syncthreads();
  const int m = min(bfill[b], CAPB);
  const int2* reg = bbuf + (size_t)b * CAPB;
  for (int i = t; i < m; i += 256) {
    int dl = ((unsigned)reg[i].y) >> 21;
    atomicAdd(&h[dl], 1);
  }
  __syncthreads();
  int node = b * GSZ + t;
  if (node < n) cnt[node] = h[t];
}

__global__ __launch_bounds__(256) void scan1_kernel(const int* __restrict__ cnt,
                                                    int* __restrict__ rowp,
                                                    int* __restrict__ bsum,
                                                    int n) {
  __shared__ int sd[256];
  const int t = threadIdx.x;
  const int base = blockIdx.x * 1024 + t * 4;
  int v0 = (base + 0 < n) ? cnt[base + 0] + 1 : 0;
  int v1 = (base + 1 < n) ? cnt[base + 1] + 1 : 0;
  int v2 = (base + 2 < n) ? cnt[base + 2] + 1 : 0;
  int v3 = (base + 3 < n) ? cnt[base + 3] + 1 : 0;
  const int s = v0 + v1 + v2 + v3;
  sd[t] = s;
  __syncthreads();
  int acc = s;
#pragma unroll
  for (int o = 1; o < 256; o <<= 1) {
    int u = (t >= o) ? sd[t - o] : 0;
    __syncthreads();
    acc += u;
    sd[t] = acc;
    __syncthreads();
  }
  int excl = acc - s;
  if (base + 0 < n) rowp[base + 0] = excl;
  if (base + 1 < n) rowp[base + 1] = excl + v0;
  if (base + 2 < n) rowp[base + 2] = excl + v0 + v1;
  if (base + 3 < n) rowp[base + 3] = excl + v0 + v1 + v2;
  if (t == 255) bsum[blockIdx.x] = acc;
}

__global__ void scan2_kernel(int* __restrict__ bsum, int nb) {
  const int lane = threadIdx.x;
  int v = (lane < nb) ? bsum[lane] : 0;
  int incl = v;
#pragma unroll
  for (int o = 1; o < 64; o <<= 1) {
    int u = __shfl_up(incl, o);
    if (lane >= o) incl += u;
  }
  if (lane < nb) bsum[lane] = incl - v;
  if (lane == 63) bsum[nb] = incl;
}

__global__ void scan3_kernel(int* __restrict__ rowp,
                             const int* __restrict__ bsum, int n, int nb) {
  int i = blockIdx.x * 256 + threadIdx.x;
  if (i >= n) return;
  rowp[i] += bsum[i >> 10];
  if (i == 0) rowp[n] = bsum[nb];
}

__global__ __launch_bounds__(256) void place_kernel(
    const int* __restrict__ rowp, const int* __restrict__ bfill,
    const int2* __restrict__ bbuf, int* __restrict__ col_src,
    int* __restrict__ eidA, int n, int E_) {
  __shared__ int rp[GSZ + 1];
  __shared__ int cur[GSZ];
  __shared__ int2 stage[CAP_C];
  const int b = blockIdx.x;
  const int t = threadIdx.x;
  const int lo = b * GSZ;
  const int nk = min(GSZ, n - lo);
  for (int i = t; i <= nk; i += 256) rp[i] = rowp[lo + i];  // covers rp[256]!
  cur[t] = 0;
  __syncthreads();
  const int s0 = rp[0];
  const int span = rp[nk] - s0;
  const bool fits = (span <= CAP_C);
  const int m = min(bfill[b], CAPB);
  const int2* reg = bbuf + (size_t)b * CAPB;
  for (int i = t; i < m; i += 256) {
    int2 pl = reg[i];
    int dl = ((unsigned)pl.y) >> 21;
    int e2 = pl.y & 0x1FFFFF;
    int p = atomicAdd(&cur[dl], 1);
    int slot = rp[dl] + p;
    if (fits) stage[slot - s0] = make_int2(pl.x, e2);
    else { col_src[slot] = pl.x; eidA[slot] = e2; }
  }
  if (t < nk) {  // self entry: last slot of each row
    int slot = rp[t + 1] - 1;
    int node = lo + t;
    if (fits) stage[slot - s0] = make_int2(node, E_ + node);
    else { col_src[slot] = node; eidA[slot] = E_ + node; }
  }
  __syncthreads();
  if (fits) {
    for (int i = t; i < span; i += 256) {
      int2 v = stage[i];
      col_src[s0 + i] = v.x;
      eidA[s0 + i] = v.y;
    }
  }
}

// --------------------------- comb (all layers) ------------------------------
__global__ void comb_all_kernel(const float* __restrict__ We0,
                                const float* __restrict__ ae0,
                                const float* __restrict__ We1,
                                const float* __restrict__ ae1,
                                const float* __restrict__ We2,
                                const float* __restrict__ ae2,
                                const float* __restrict__ We3,
                                const float* __restrict__ ae3,
                                float* __restrict__ comb) {
  int t = threadIdx.x;
  if (t >= 48) return;
  float s = 0.f;
  if (t < 8) {
    int d = t;
    for (int c = 0; c < 64; ++c) s += We0[d * 64 + c] * ae0[c];
  } else if (t < 24) {
    int idx = t - 8, h = idx >> 3, d = idx & 7;
    for (int c = 0; c < 64; ++c) s += We1[d * 128 + h * 64 + c] * ae1[h * 64 + c];
  } else if (t < 40) {
    int idx = t - 24, h = idx >> 3, d = idx & 7;
    for (int c = 0; c < 64; ++c) s += We2[d * 128 + h * 64 + c] * ae2[h * 64 + c];
  } else {
    int d = t - 40;
    for (int c = 0; c < 2; ++c) s += We3[d * 2 + c] * ae3[c];
  }
  comb[t] = s;
}

// --------------------------- edge prep -------------------------------------
// Per-head edot planes for the H=2 layers (contiguous per-pass reads).
__global__ __launch_bounds__(256) void edge_prep_kernel(
    const int* __restrict__ row_ptr, const int* __restrict__ eid,
    const float* __restrict__ ea, const float* __restrict__ comb,
    float* __restrict__ edot0, float* __restrict__ e1a,
    float* __restrict__ e1b, float* __restrict__ e2a,
    float* __restrict__ e2b, float* __restrict__ edot3, int n, int E_) {
  __shared__ float cb[48];
  if (threadIdx.x < 48) cb[threadIdx.x] = comb[threadIdx.x];
  __syncthreads();
  const int lane = threadIdx.x & 63;
  const int node = blockIdx.x * 4 + (threadIdx.x >> 6);
  if (node >= n) return;

  const int start = row_ptr[node];
  const int selfpos = row_ptr[node + 1] - 1;  // self entry is last

  float s0 = 0.f, s1 = 0.f, s2 = 0.f, s3 = 0.f, s4 = 0.f, s5 = 0.f, s6 = 0.f,
        s7 = 0.f;
  for (int i = start + lane; i < selfpos; i += 64) {
    int id = eid[i];
    const float4* v = reinterpret_cast<const float4*>(ea + (size_t)id * 8);
    float4 a = v[0], b = v[1];
    s0 += a.x; s1 += a.y; s2 += a.z; s3 += a.w;
    s4 += b.x; s5 += b.y; s6 += b.z; s7 += b.w;
    edot0[i] = dot8(a, b, cb + 0);
    e1a[i] = dot8(a, b, cb + 8);
    e1b[i] = dot8(a, b, cb + 16);
    e2a[i] = dot8(a, b, cb + 24);
    e2b[i] = dot8(a, b, cb + 32);
    edot3[i] = dot8(a, b, cb + 40);
  }
#pragma unroll
  for (int o = 32; o >= 1; o >>= 1) {
    s0 += __shfl_xor(s0, o); s1 += __shfl_xor(s1, o);
    s2 += __shfl_xor(s2, o); s3 += __shfl_xor(s3, o);
    s4 += __shfl_xor(s4, o); s5 += __shfl_xor(s5, o);
    s6 += __shfl_xor(s6, o); s7 += __shfl_xor(s7, o);
  }
  if (lane == 0) {
    float deg = (float)(selfpos - start);
    float inv = 1.f / fmaxf(deg, 1.f);
    float4 a = make_float4(s0 * inv, s1 * inv, s2 * inv, s3 * inv);
    float4 b = make_float4(s4 * inv, s5 * inv, s6 * inv, s7 * inv);
    int i = selfpos;
    edot0[i] = dot8(a, b, cb + 0);
    e1a[i] = dot8(a, b, cb + 8);
    e1b[i] = dot8(a, b, cb + 16);
    e2a[i] = dot8(a, b, cb + 24);
    e2b[i] = dot8(a, b, cb + 32);
    edot3[i] = dot8(a, b, cb + 40);
  }
}

// --------------------------- projection GEMM -------------------------------
// h = x @ W; H==2: head-major planes h + h*n*64. al_src/al_dst head-major
// [h][n] (H==1 indexing degenerates to [n]).
template <int HC, int H>
__global__ __launch_bounds__(256) void gemm_proj_kernel(
    const float* __restrict__ x, const float* __restrict__ W,
    const float* __restrict__ a_src, const float* __restrict__ a_dst,
    float* __restrict__ h, float* __restrict__ al_src,
    float* __restrict__ al_dst, int n) {
  constexpr int IN = 64;
  constexpr int C = HC / H;
  __shared__ float xs[32][IN];
  const int tid = threadIdx.x;
  const int j = tid % HC;
  const int rsub = tid / HC;
  constexpr int RPP = 256 / HC > 0 ? 256 / HC : 1;

  float wr[IN];
#pragma unroll
  for (int k = 0; k < IN; ++k) wr[k] = W[k * HC + j];
  const float asj = a_src[j];
  const float adj = a_dst[j];

  const int row0 = blockIdx.x * 32;
  {
    const float4* xv = reinterpret_cast<const float4*>(x);
    float4* xsv = reinterpret_cast<float4*>(&xs[0][0]);
    for (int i = tid; i < 32 * IN / 4; i += 256) {
      int r = i / (IN / 4);
      int row = row0 + r;
      float4 v = make_float4(0.f, 0.f, 0.f, 0.f);
      if (row < n) v = xv[(size_t)row * (IN / 4) + (i % (IN / 4))];
      xsv[i] = v;
    }
  }
  __syncthreads();

  for (int rb = 0; rb < 32; rb += RPP) {
    int r = rb + rsub;
    if (r >= 32) break;  // wave-uniform (only for HC=2 tails)
    int row = row0 + r;
    float acc = 0.f;
#pragma unroll
    for (int k4 = 0; k4 < IN / 4; ++k4) {
      float4 xv = *reinterpret_cast<const float4*>(&xs[r][k4 * 4]);
      acc += xv.x * wr[k4 * 4 + 0] + xv.y * wr[k4 * 4 + 1] +
             xv.z * wr[k4 * 4 + 2] + xv.w * wr[k4 * 4 + 3];
    }
    if (row < n) {
      size_t oidx = (H == 2)
                        ? ((size_t)(j >> 6) * ((size_t)n * 64) +
                           (size_t)row * 64 + (j & 63))
                        : ((size_t)row * HC + j);
      h[oidx] = acc;
    }
    float ps = acc * asj;
    float pd = acc * adj;
#pragma unroll
    for (int o = C / 2; o >= 1; o >>= 1) {
      ps += __shfl_xor(ps, o);
      pd += __shfl_xor(pd, o);
    }
    if (row < n && (j % C) == 0) {
      int hh = j / C;
      al_src[(size_t)hh * n + row] = ps;
      al_dst[(size_t)hh * n + row] = pd;
    }
  }
}

// ------------------- fused node kernel (H=1 layers) -------------------------
template <int C, bool RELU>
__global__ __launch_bounds__(256) void gat_node_kernel(
    const int* __restrict__ row_ptr, const int* __restrict__ col_src,
    const float* __restrict__ edot, const float* __restrict__ h_proj,
    const float* __restrict__ al_src, const float* __restrict__ al_dst,
    const float* __restrict__ bias, float* __restrict__ out, int n) {
  const int lane = threadIdx.x & 63;
  const int node = blockIdx.x * 4 + (threadIdx.x >> 6);
  if (node >= n) return;

  const float adn = al_dst[node];
  const int start = row_ptr[node];
  const int end = row_ptr[node + 1];

  float denp = 0.f;
  float4 acc4 = make_float4(0.f, 0.f, 0.f, 0.f);
  float accp = 0.f;  // C==2 path accumulator

  const int sub = lane & 15;    // channel quad
  const int grp16 = lane >> 4;  // edge slot within group-of-4

  for (int base = start; base < end; base += 64) {
    const int i = base + lane;
    const bool valid = (i < end);
    int s = 0;
    float ex = 0.f;
    if (valid) {
      s = col_src[i];
      float a = al_src[s] + adn + edot[i];
      a = (a > 0.f) ? a : 0.2f * a;
      ex = __expf(a);
    }
    denp += ex;

    const int cntc = min(64, end - base);
    if (C == 2) {
      const int half = lane >> 1;
      const int ch = lane & 1;
#pragma unroll
      for (int sb = 0; sb < 2; ++sb) {
        int tt = sb * 32 + half;
        int sv = __shfl(s, tt);
        float w = __shfl(ex, tt);
        if (tt < cntc) accp += w * h_proj[sv * 2 + ch];
      }
    } else {
      // register ping-pong: two 4-load batches in flight
      auto issue = [&](int g, float4 (&v)[4], float (&w)[4]) {
#pragma unroll
        for (int u = 0; u < 4; ++u) {
          int tt = (g * 4 + u) * 4 + grp16;  // <= 63; overshoot lanes ex=0
          int sv = __shfl(s, tt);
          w[u] = __shfl(ex, tt);
          v[u] = *reinterpret_cast<const float4*>(h_proj + (size_t)sv * 64 +
                                                  sub * 4);
        }
      };
      auto fma4 = [&](float4 (&v)[4], float (&w)[4]) {
#pragma unroll
        for (int u = 0; u < 4; ++u) {
          acc4.x += w[u] * v[u].x; acc4.y += w[u] * v[u].y;
          acc4.z += w[u] * v[u].z; acc4.w += w[u] * v[u].w;
        }
      };
      const int nbat = (cntc + 15) >> 4;  // batches of 16 edges, <= 4
      float4 va[4], vb[4];
      float wa[4], wb[4];
      issue(0, va, wa);
      int g = 0;
      for (;;) {
        if (g + 1 < nbat) issue(g + 1, vb, wb);
        fma4(va, wa);
        if (++g >= nbat) break;
        if (g + 1 < nbat) issue(g + 1, va, wa);
        fma4(vb, wb);
        if (++g >= nbat) break;
      }
    }
  }

  const float den = wave_sum64(denp);

  if (C == 2) {
#pragma unroll
    for (int o = 2; o <= 32; o <<= 1) accp += __shfl_xor(accp, o);
    if (lane < 2) {
      float v = accp / (den + 1e-16f) + bias[lane];
      if (RELU) v = fmaxf(v, 0.f);
      out[node * 2 + lane] = v;
    }
  } else {
    acc4.x += __shfl_xor(acc4.x, 16); acc4.x += __shfl_xor(acc4.x, 32);
    acc4.y += __shfl_xor(acc4.y, 16); acc4.y += __shfl_xor(acc4.y, 32);
    acc4.z += __shfl_xor(acc4.z, 16); acc4.z += __shfl_xor(acc4.z, 32);
    acc4.w += __shfl_xor(acc4.w, 16); acc4.w += __shfl_xor(acc4.w, 32);
    if (lane < 16) {
      float inv = 1.f / (den + 1e-16f);
      float4 bv = *reinterpret_cast<const float4*>(bias + sub * 4);
      float4 o;
      o.x = acc4.x * inv + bv.x; o.y = acc4.y * inv + bv.y;
      o.z = acc4.z * inv + bv.z; o.w = acc4.w * inv + bv.w;
      if (RELU) {
        o.x = fmaxf(o.x, 0.f); o.y = fmaxf(o.y, 0.f);
        o.z = fmaxf(o.z, 0.f); o.w = fmaxf(o.w, 0.f);
      }
      *reinterpret_cast<float4*>(out + (size_t)node * 64 + sub * 4) = o;
    }
  }
}

// ------------------- per-head pass kernel (H=2 layers) ----------------------
template <bool FIRST>
__global__ __launch_bounds__(256) void gat_head_kernel(
    const int* __restrict__ row_ptr, const int* __restrict__ col_src,
    const float* __restrict__ edotH, const float* __restrict__ hplane,
    const float* __restrict__ al_srcH, const float* __restrict__ al_dstH,
    const float* __restrict__ bias, float* __restrict__ partial,
    float* __restrict__ out, int n) {
  const int lane = threadIdx.x & 63;
  const int node = blockIdx.x * 4 + (threadIdx.x >> 6);
  if (node >= n) return;

  const float adn = al_dstH[node];
  const int start = row_ptr[node];
  const int end = row_ptr[node + 1];

  float denp = 0.f;
  float4 acc4 = make_float4(0.f, 0.f, 0.f, 0.f);

  const int sub = lane & 15;
  const int grp16 = lane >> 4;

  for (int base = start; base < end; base += 64) {
    const int i = base + lane;
    const bool valid = (i < end);
    int s = 0;
    float ex = 0.f;
    if (valid) {
      s = col_src[i];
      float a = al_srcH[s] + adn + edotH[i];
      a = (a > 0.f) ? a : 0.2f * a;
      ex = __expf(a);
    }
    denp += ex;

    const int cntc = min(64, end - base);
    auto issue = [&](int g, float4 (&v)[4], float (&w)[4]) {
#pragma unroll
      for (int u = 0; u < 4; ++u) {
        int tt = (g * 4 + u) * 4 + grp16;  // <= 63; overshoot lanes ex=0
        int sv = __shfl(s, tt);
        w[u] = __shfl(ex, tt);
        v[u] = *reinterpret_cast<const float4*>(hplane + (size_t)sv * 64 +
                                                sub * 4);
      }
    };
    auto fma4 = [&](float4 (&v)[4], float (&w)[4]) {
#pragma unroll
      for (int u = 0; u < 4; ++u) {
        acc4.x += w[u] * v[u].x; acc4.y += w[u] * v[u].y;
        acc4.z += w[u] * v[u].z; acc4.w += w[u] * v[u].w;
      }
    };
    const int nbat = (cntc + 15) >> 4;  // batches of 16 edges, <= 4
    float4 va[4], vb[4];
    float wa[4], wb[4];
    issue(0, va, wa);
    int g = 0;
    for (;;) {
      if (g + 1 < nbat) issue(g + 1, vb, wb);
      fma4(va, wa);
      if (++g >= nbat) break;
      if (g + 1 < nbat) issue(g + 1, va, wa);
      fma4(vb, wb);
      if (++g >= nbat) break;
    }
  }

  const float den = wave_sum64(denp);

  acc4.x += __shfl_xor(acc4.x, 16); acc4.x += __shfl_xor(acc4.x, 32);
  acc4.y += __shfl_xor(acc4.y, 16); acc4.y += __shfl_xor(acc4.y, 32);
  acc4.z += __shfl_xor(acc4.z, 16); acc4.z += __shfl_xor(acc4.z, 32);
  acc4.w += __shfl_xor(acc4.w, 16); acc4.w += __shfl_xor(acc4.w, 32);
  if (lane < 16) {
    float inv = 1.f / (den + 1e-16f);
    if (FIRST) {
      float4 o;
      o.x = acc4.x * inv; o.y = acc4.y * inv;
      o.z = acc4.z * inv; o.w = acc4.w * inv;
      *reinterpret_cast<float4*>(partial + (size_t)node * 64 + sub * 4) = o;
    } else {
      float4 p =
          *reinterpret_cast<const float4*>(partial + (size_t)node * 64 + sub * 4);
      float4 bv = *reinterpret_cast<const float4*>(bias + sub * 4);
      float4 o;
      o.x = fmaxf((p.x + acc4.x * inv) * 0.5f + bv.x, 0.f);
      o.y = fmaxf((p.y + acc4.y * inv) * 0.5f + bv.y, 0.f);
      o.z = fmaxf((p.z + acc4.z * inv) * 0.5f + bv.z, 0.f);
      o.w = fmaxf((p.w + acc4.w * inv) * 0.5f + bv.w, 0.f);
      *reinterpret_cast<float4*>(out + (size_t)node * 64 + sub * 4) = o;
    }
  }
}

// --------------------------- launch ----------------------------------------

static inline size_t align_up(size_t v, size_t a) { return (v + a - 1) & ~(a - 1); }

extern "C" void kernel_launch(void* const* d_in, const int* in_sizes, int n_in,
                              void* d_out, int out_size, void* d_ws,
                              size_t ws_size, hipStream_t stream) {
  const float* x = (const float*)d_in[0];
  const int* ei = (const int*)d_in[1];
  const float* ea = (const float*)d_in[2];

  const int N = in_sizes[0] / 64;
  const int E = in_sizes[1] / 2;
  const int* src0 = ei;
  const int* dst0 = ei + E;
  const int M = E + N;  // CSR slots

  const float* W[4] = {(const float*)d_in[3], (const float*)d_in[9],
                       (const float*)d_in[15], (const float*)d_in[21]};
  const float* As[4] = {(const float*)d_in[4], (const float*)d_in[10],
                        (const float*)d_in[16], (const float*)d_in[22]};
  const float* Ad[4] = {(const float*)d_in[5], (const float*)d_in[11],
                        (const float*)d_in[17], (const float*)d_in[23]};
  const float* We[4] = {(const float*)d_in[6], (const float*)d_in[12],
                        (const float*)d_in[18], (const float*)d_in[24]};
  const float* Ae[4] = {(const float*)d_in[7], (const float*)d_in[13],
                        (const float*)d_in[19], (const float*)d_in[25]};
  const float* B[4] = {(const float*)d_in[8], (const float*)d_in[14],
                       (const float*)d_in[20], (const float*)d_in[26]};

  // workspace carve-up
  char* p = (char*)d_ws;
  size_t off = 0;
  auto carve = [&](size_t bytes) {
    void* r = p + off;
    off = align_up(off + bytes, 256);
    return r;
  };
  const int NBK = (N + GSZ - 1) / GSZ;  // coarse buckets (196 for N=50000)
  int* cnt = (int*)carve((size_t)N * 4);
  int* row_ptr = (int*)carve((size_t)(N + 1) * 4);
  int* bsum = (int*)carve((size_t)256 * 4);
  int* bfill = (int*)carve((size_t)NBK * 4);
  int2* bbuf = (int2*)carve((size_t)NBK * CAPB * 8);  // reused as `partial`
  int* col_src = (int*)carve((size_t)M * 4);
  int* eid = (int*)carve((size_t)M * 4);
  float* comb = (float*)carve(256);
  float* edot0 = (float*)carve((size_t)M * 4);
  float* e1a = (float*)carve((size_t)M * 4);
  float* e1b = (float*)carve((size_t)M * 4);
  float* e2a = (float*)carve((size_t)M * 4);
  float* e2b = (float*)carve((size_t)M * 4);
  float* edot3 = (float*)carve((size_t)M * 4);
  float* al_src = (float*)carve((size_t)N * 2 * 4);
  float* al_dst = (float*)carve((size_t)N * 2 * 4);
  float* h_proj = (float*)carve((size_t)N * 128 * 4);
  float* buf_a = (float*)carve((size_t)N * 64 * 4);
  float* buf_b = (float*)carve((size_t)N * 64 * 4);
  float* partial = (float*)bbuf;  // 16 MB region, dead after CSR build; need 12.8
  (void)ws_size;

  const int nb = (N + 1023) / 1024;  // <=64 required (N<=65536)

  // ---- CSR + per-edge dots (graph is layer-invariant) ----
  hipMemsetAsync(bfill, 0, (size_t)NBK * 4, stream);
  bin_kernel<<<(E + CHUNK - 1) / CHUNK, 256, 0, stream>>>(src0, dst0, bfill,
                                                          bbuf, E);
  count_kernel<<<NBK, 256, 0, stream>>>(bfill, bbuf, cnt, N);
  scan1_kernel<<<nb, 256, 0, stream>>>(cnt, row_ptr, bsum, N);
  scan2_kernel<<<1, 64, 0, stream>>>(bsum, nb);
  scan3_kernel<<<(N + 255) / 256, 256, 0, stream>>>(row_ptr, bsum, N, nb);
  place_kernel<<<NBK, 256, 0, stream>>>(row_ptr, bfill, bbuf, col_src, eid, N,
                                        E);
  comb_all_kernel<<<1, 64, 0, stream>>>(We[0], Ae[0], We[1], Ae[1], We[2],
                                        Ae[2], We[3], Ae[3], comb);
  edge_prep_kernel<<<(N + 3) / 4, 256, 0, stream>>>(
      row_ptr, eid, ea, comb, edot0, e1a, e1b, e2a, e2b, edot3, N, E);

  const int gemm_grid = (N + 31) / 32;
  const int node_grid = (N + 3) / 4;
  const size_t plane = (size_t)N * 64;

  // ---- layer 0: in64 -> H1,C64, concat, relu ----
  gemm_proj_kernel<64, 1><<<gemm_grid, 256, 0, stream>>>(
      x, W[0], As[0], Ad[0], h_proj, al_src, al_dst, N);
  gat_node_kernel<64, true><<<node_grid, 256, 0, stream>>>(
      row_ptr, col_src, edot0, h_proj, al_src, al_dst, B[0], buf_a, N);

  // ---- layer 1: 64 -> H2,C64, mean, relu (two per-head passes) ----
  gemm_proj_kernel<128, 2><<<gemm_grid, 256, 0, stream>>>(
      buf_a, W[1], As[1], Ad[1], h_proj, al_src, al_dst, N);
  gat_head_kernel<true><<<node_grid, 256, 0, stream>>>(
      row_ptr, col_src, e1a, h_proj, al_src, al_dst, B[1], partial, nullptr, N);
  gat_head_kernel<false><<<node_grid, 256, 0, stream>>>(
      row_ptr, col_src, e1b, h_proj + plane, al_src + N, al_dst + N, B[1],
      partial, buf_b, N);

  // ---- layer 2: 64 -> H2,C64, mean, relu (two per-head passes) ----
  gemm_proj_kernel<128, 2><<<gemm_grid, 256, 0, stream>>>(
      buf_b, W[2], As[2], Ad[2], h_proj, al_src, al_dst, N);
  gat_head_kernel<true><<<node_grid, 256, 0, stream>>>(
      row_ptr, col_src, e2a, h_proj, al_src, al_dst, B[2], partial, nullptr, N);
  gat_head_kernel<false><<<node_grid, 256, 0, stream>>>(
      row_ptr, col_src, e2b, h_proj + plane, al_src + N, al_dst + N, B[2],
      partial, buf_a, N);

  // ---- layer 3: 64 -> H1,C2, concat, no relu ----
  gemm_proj_kernel<2, 1><<<gemm_grid, 256, 0, stream>>>(
      buf_a, W[3], As[3], Ad[3], h_proj, al_src, al_dst, N);
  gat_node_kernel<2, false><<<node_grid, 256, 0, stream>>>(
      row_ptr, col_src, edot3, h_proj, al_src, al_dst, B[3], (float*)d_out, N);
}